// Round 2
// baseline (377.129 us; speedup 1.0000x reference)
//
#include <hip/hip_runtime.h>

typedef __attribute__((ext_vector_type(8))) short short8;
typedef __attribute__((ext_vector_type(4))) float f32x4;
typedef __attribute__((ext_vector_type(16))) float f32x16;
typedef __attribute__((ext_vector_type(4))) float fvec4;
typedef __attribute__((ext_vector_type(4))) unsigned short us4;

#define T_ 2048
#define D_ 512
#define SC_ 0.04419417382415922f   // 1/sqrt(512)

__device__ __forceinline__ unsigned short f2bf(float f) {
    unsigned int u = __float_as_uint(f);
    u += 0x7fffu + ((u >> 16) & 1u);
    return (unsigned short)(u >> 16);
}

// async global->LDS, 16B per lane; LDS dest = wave-uniform base + lane*16
__device__ __forceinline__ void gload16(const void* g, void* l) {
    __builtin_amdgcn_global_load_lds((const __attribute__((address_space(1))) unsigned int*)g,
                                     (__attribute__((address_space(3))) unsigned int*)l,
                                     16, 0, 0);
}

// ---------------------------------------------------------------- merged prep
__global__ __launch_bounds__(256) void prep_all(
    const float* __restrict__ in_f,
    const float* __restrict__ Wq, const float* __restrict__ Wk,
    const float* __restrict__ Wv, const float* __restrict__ Wr,
    unsigned short* __restrict__ in_bf,
    unsigned short* __restrict__ WqT, unsigned short* __restrict__ WkT,
    unsigned short* __restrict__ WvT, unsigned short* __restrict__ WrT,
    unsigned short* __restrict__ pe)
{
    const int bb = blockIdx.x;
    const int tid = threadIdx.x;
    if (bb < 8192) {
        const int idx = bb * 256 + tid;
        fvec4 v = ((const fvec4*)in_f)[idx];
        us4 o;
        o.x = f2bf(v.x); o.y = f2bf(v.y); o.z = f2bf(v.z); o.w = f2bf(v.w);
        ((us4*)in_bf)[idx] = o;
    } else if (bb < 9216) {
        __shared__ float wt[32][33];              // padded: no bank conflicts
        const int t = bb - 8192;                  // 0..1023
        const int w = t >> 8, tile = t & 255;
        const int tr = (tile >> 4) * 32, tc = (tile & 15) * 32;
        const float* W = (w == 0) ? Wq : (w == 1) ? Wk : (w == 2) ? Wv : Wr;
        unsigned short* WT = (w == 0) ? WqT : (w == 1) ? WkT : (w == 2) ? WvT : WrT;
        const int r0 = tid >> 5, c0 = tid & 31;
#pragma unroll
        for (int p = 0; p < 4; ++p)
            wt[r0 + 8 * p][c0] = W[(long)(tr + r0 + 8 * p) * 512 + tc + c0];
        __syncthreads();
#pragma unroll
        for (int p = 0; p < 4; ++p)
            WT[(long)(tc + r0 + 8 * p) * 512 + tr + c0] = f2bf(wt[c0][r0 + 8 * p]);
    } else {
        const int idx = (bb - 9216) * 256 + tid;  // 0..262143 us4 chunks
        const int o = idx * 4;
        const int rpos = o >> 9;
        us4 ov;
#pragma unroll
        for (int e = 0; e < 4; ++e) {
            const int c = (o + e) & 511;
            const int ci = (c < 256) ? c : c - 256;
            const float dv = expf((float)ci * -0.03611898183128701f);  // -log(1e4)/255
            const float ang = (float)rpos * dv;
            ((unsigned short*)&ov)[e] = f2bf((c < 256) ? sinf(ang) : cosf(ang));
        }
        ((us4*)pe)[idx] = ov;
    }
}

// ---------------------------------------------------------------- GEMM core
// BK=64. LDS tile [128][64] bf16 (16 KB each). Element (row,c) lives in 16B
// chunk (row, (c/8) ^ (row&7)) — XOR swizzle: 0 bank conflicts (verified R5/R6;
// 8-lane phase groups each cover 8 distinct chunks for the 32x32 pattern too).
struct __align__(16) SMem {
    unsigned short At[128 * 64];   // 16 KB
    unsigned short Bt[128 * 64];   // 16 KB
};

// 32x32x16 MFMA: A row=lane&31, k=(lane>>5)*8+e ; C/D col=lane&31,
// row=(reg&3)+8*(reg>>2)+4*(lane>>5)  [verified m74/m101]
__device__ __forceinline__ void gemm_core(const unsigned short* __restrict__ A, long lda,
                                          const unsigned short* __restrict__ B, long ldb,
                                          int kmax, SMem& sm, f32x16 (&acc)[2][2]) {
    const int tid = threadIdx.x;
    const int wid = tid >> 6;
    const int lane = tid & 63;
    const int l31 = lane & 31;
    const int hi = lane >> 5;
    const int wm = (wid & 1) * 64;
    const int wn = (wid >> 1) * 64;
#pragma unroll
    for (int r = 0; r < 2; ++r)
#pragma unroll
        for (int c = 0; c < 2; ++c)
#pragma unroll
            for (int e = 0; e < 16; ++e) acc[r][c][e] = 0.f;

    const int sr = tid >> 3;                             // staging row 0..31
    const int l8 = ((tid & 7) ^ (sr & 7)) * 8;           // swizzled source chunk
    const unsigned short* Ag = A + (long)sr * lda + l8;
    const unsigned short* Bg = B + (long)sr * ldb + l8;

    for (int kk = 0; kk < kmax; kk += 64) {
#pragma unroll
        for (int c = 0; c < 4; ++c) {                    // rows 32c..32c+31
            gload16(Ag + (long)(32 * c) * lda + kk, &sm.At[c * 2048 + wid * 512]);
            gload16(Bg + (long)(32 * c) * ldb + kk, &sm.Bt[c * 2048 + wid * 512]);
        }
        __syncthreads();
#pragma unroll
        for (int ks = 0; ks < 4; ++ks) {                 // K=16 per step
            short8 av[2], bv[2];
#pragma unroll
            for (int r = 0; r < 2; ++r) {
                const int row = wm + r * 32 + l31;
                av[r] = *(const short8*)&sm.At[row * 64 + (((ks * 2 + hi) ^ (row & 7)) * 8)];
            }
#pragma unroll
            for (int c = 0; c < 2; ++c) {
                const int row = wn + c * 32 + l31;
                bv[c] = *(const short8*)&sm.Bt[row * 64 + (((ks * 2 + hi) ^ (row & 7)) * 8)];
            }
#pragma unroll
            for (int r = 0; r < 2; ++r)
#pragma unroll
                for (int c = 0; c < 2; ++c)
                    acc[r][c] = __builtin_amdgcn_mfma_f32_32x32x16_bf16(av[r], bv[c], acc[r][c], 0, 0, 0);
        }
        __syncthreads();
    }
}

#define EPI_COORDS()                               \
    const int tid = threadIdx.x;                   \
    const int wid = tid >> 6;                      \
    const int lane = tid & 63;                     \
    const int l31 = lane & 31;                     \
    const int hi = lane >> 5;                      \
    const int wm = (wid & 1) * 64;                 \
    const int wn = (wid >> 1) * 64;                \
    (void)tid;

// ---------------------------------------------------------------- phase kernels
__global__ __launch_bounds__(256, 3) void proj_kernel(
    const unsigned short* __restrict__ in_bf,
    const unsigned short* __restrict__ WqT, const unsigned short* __restrict__ WkT,
    const unsigned short* __restrict__ WvT, const unsigned short* __restrict__ WrT,
    const unsigned short* __restrict__ pe,
    const float* __restrict__ cb, const float* __restrict__ rb,
    unsigned short* __restrict__ qc, unsigned short* __restrict__ qr,
    unsigned short* __restrict__ kbf, unsigned short* __restrict__ vT,
    unsigned short* __restrict__ rk)
{
    __shared__ SMem sm;
    EPI_COORDS();
    const long TD = (long)T_ * D_;
    const long DT = (long)D_ * T_;
    f32x16 acc[2][2];
    const int t = blockIdx.x;   // 0..1599
    if (t < 1024) {                           // qc/qr (t<512) and k (t<1024)
        const int r = t & 511;
        const int it = r >> 2, jt = r & 3;
        const unsigned short* Bw = (t < 512) ? WqT : WkT;
        gemm_core(in_bf + (long)it * 128 * 512, 512, Bw + (long)jt * 128 * 512, 512, 512, sm, acc);
        const int i0 = it * 128, j0 = jt * 128;
#pragma unroll
        for (int r2 = 0; r2 < 2; ++r2)
#pragma unroll
            for (int c2 = 0; c2 < 2; ++c2) {
                const int gj = j0 + wn + c2 * 32 + l31;
#pragma unroll
                for (int reg = 0; reg < 16; ++reg) {
                    const int rl = (reg & 3) + 8 * (reg >> 2) + 4 * hi;
                    const long row = i0 + wm + r2 * 32 + rl;
                    const float v = acc[r2][c2][reg];
                    if (t < 512) {
                        qc[row * 512 + gj] = f2bf(v + cb[gj]);
                        qr[row * 512 + gj] = f2bf(v + rb[gj]);
                    } else {
                        kbf[row * 512 + gj] = f2bf(v);
                    }
                }
            }
    } else if (t < 1536) {                    // vT[b] = Wv^T @ in[b]^T
        const int r = t - 1024;
        const int z = r >> 6, rr = r & 63;
        const int it = rr >> 4, jt = rr & 15;
        const int i0 = it * 128, j0 = jt * 128;
        gemm_core(WvT + (long)i0 * 512, 512, in_bf + (long)z * TD + (long)j0 * 512, 512, 512, sm, acc);
#pragma unroll
        for (int r2 = 0; r2 < 2; ++r2)
#pragma unroll
            for (int c2 = 0; c2 < 2; ++c2) {
                const int gj = j0 + wn + c2 * 32 + l31;
#pragma unroll
                for (int reg = 0; reg < 16; ++reg) {
                    const int rl = (reg & 3) + 8 * (reg >> 2) + 4 * hi;
                    const int gi = i0 + wm + r2 * 32 + rl;
                    vT[(long)z * DT + (long)gi * 2048 + gj] = f2bf(acc[r2][c2][reg]);
                }
            }
    } else {                                  // rk = pe @ Wrel
        const int r = t - 1536;
        const int it = r >> 2, jt = r & 3;
        const int i0 = it * 128, j0 = jt * 128;
        gemm_core(pe + (long)i0 * 512, 512, WrT + (long)j0 * 512, 512, 512, sm, acc);
#pragma unroll
        for (int r2 = 0; r2 < 2; ++r2)
#pragma unroll
            for (int c2 = 0; c2 < 2; ++c2) {
                const int gj = j0 + wn + c2 * 32 + l31;
#pragma unroll
                for (int reg = 0; reg < 16; ++reg) {
                    const int rl = (reg & 3) + 8 * (reg >> 2) + 4 * hi;
                    const int gi = i0 + wm + r2 * 32 + rl;
                    rk[(long)gi * 512 + gj] = f2bf(acc[r2][c2][reg]);
                }
            }
    }
}

// content scores -> C8 (pre-scaled, causal tiles) and rel scores -> R8.
// R8 is written SHIFTED and PRE-SCALED: Rs[i][j] = SC * R[i][p], j = p + i - 2047.
// XCD-aware: z = blockIdx & 7 so each XCD works one batch.
__global__ __launch_bounds__(256, 3) void score_kernel(
    const unsigned short* __restrict__ qc, const unsigned short* __restrict__ qr,
    const unsigned short* __restrict__ kbf, const unsigned short* __restrict__ rk,
    float* __restrict__ C8, float* __restrict__ R8)
{
    __shared__ SMem sm;
    EPI_COORDS();
    const long TD = (long)T_ * D_;
    f32x16 acc[2][2];
    const int z = blockIdx.x & 7;             // XCD cluster by batch
    const int rr = blockIdx.x >> 3;           // 0..271
    if (rr < 136) {
        const int r = rr;
        int a = (int)((sqrtf(8.f * (float)r + 1.f) - 1.f) * 0.5f);
        if ((a + 1) * (a + 2) / 2 <= r) ++a;
        if (a * (a + 1) / 2 > r) --a;
        const int b = r - a * (a + 1) / 2;    // b <= a (causal tiles)
        const int i0 = a * 128, j0 = b * 128;
        gemm_core(qc + (long)z * TD + (long)i0 * 512, 512,
                  kbf + (long)z * TD + (long)j0 * 512, 512, 512, sm, acc);
        float* Cf = C8 + (long)z * 4194304L;
#pragma unroll
        for (int r2 = 0; r2 < 2; ++r2)
#pragma unroll
            for (int c2 = 0; c2 < 2; ++c2) {
                const int gj = j0 + wn + c2 * 32 + l31;
#pragma unroll
                for (int reg = 0; reg < 16; ++reg) {
                    const int rl = (reg & 3) + 8 * (reg >> 2) + 4 * hi;
                    const int gi = i0 + wm + r2 * 32 + rl;
                    Cf[(long)gi * 2048 + gj] = acc[r2][c2][reg] * SC_;
                }
            }
    } else {
        const int r = rr - 136;
        int u = (int)((sqrtf(8.f * (float)r + 1.f) - 1.f) * 0.5f);
        if ((u + 1) * (u + 2) / 2 <= r) ++u;
        if (u * (u + 1) / 2 > r) --u;
        const int v2 = r - u * (u + 1) / 2;   // v2 <= u
        const int a = u, b = 15 - u + v2;     // tiles covering p >= T-1-i
        const int i0 = a * 128, p0 = b * 128;
        gemm_core(qr + (long)z * TD + (long)i0 * 512, 512,
                  rk + (long)p0 * 512, 512, 512, sm, acc);
        float* Rf = R8 + (long)z * 4194304L;
#pragma unroll
        for (int r2 = 0; r2 < 2; ++r2)
#pragma unroll
            for (int c2 = 0; c2 < 2; ++c2) {
                const int gp = p0 + wn + c2 * 32 + l31;
#pragma unroll
                for (int reg = 0; reg < 16; ++reg) {
                    const int rl = (reg & 3) + 8 * (reg >> 2) + 4 * hi;
                    const int row = i0 + wm + r2 * 32 + rl;
                    const int j = gp + row - 2047;       // shifted column
                    if (j >= 0)
                        Rf[(long)row * 2048 + j] = acc[r2][c2][reg] * SC_;
                }
            }
    }
}

// row softmax: S[i,j] = C8[i,j] + Rs[i,j] (both pre-scaled, row-aligned).
// One row per block, grid (2048, 8). float4 loads, us4 stores.
__global__ __launch_bounds__(256) void softmax_kernel(float* __restrict__ C8,
                                                      const float* __restrict__ R8) {
    const int i = blockIdx.x;
    float* Cm = C8 + (long)blockIdx.y * 4194304L;
    const float* Rm = R8 + (long)blockIdx.y * 4194304L;
    __shared__ float s[2048];
    __shared__ float red[5];
    const int tid = threadIdx.x;
    const int wid = tid >> 6;
    const int n = i + 1;
    const int n4 = (n + 3) >> 2;
    const f32x4* c4 = (const f32x4*)(Cm + (long)i * 2048);
    const f32x4* r4 = (const f32x4*)(Rm + (long)i * 2048);
    float lmax = -3.0e38f;
    for (int j4 = tid; j4 < n4; j4 += 256) {
        const f32x4 c = c4[j4];
        const f32x4 r = r4[j4];
        f32x4 v;
#pragma unroll
        for (int e = 0; e < 4; ++e) {
            const int j = j4 * 4 + e;
            const float vv = (j < n) ? c[e] + r[e] : -3.0e38f;   // mask tail/poison
            v[e] = vv;
            lmax = fmaxf(lmax, vv);
        }
        *(f32x4*)&s[j4 * 4] = v;
    }
    for (int o = 32; o; o >>= 1) lmax = fmaxf(lmax, __shfl_down(lmax, o));
    if ((tid & 63) == 0) red[wid] = lmax;
    __syncthreads();
    if (tid == 0) red[4] = fmaxf(fmaxf(red[0], red[1]), fmaxf(red[2], red[3]));
    __syncthreads();
    const float m = red[4];
    float lsum = 0.f;
    for (int j4 = tid; j4 < n4; j4 += 256) {
        f32x4 v = *(f32x4*)&s[j4 * 4];
#pragma unroll
        for (int e = 0; e < 4; ++e) {
            const float x = __expf(v[e] - m);      // masked lanes -> exp(-inf)=0
            v[e] = x;
            lsum += x;
        }
        *(f32x4*)&s[j4 * 4] = v;
    }
    for (int o = 32; o; o >>= 1) lsum += __shfl_down(lsum, o);
    if ((tid & 63) == 0) red[wid] = lsum;
    __syncthreads();
    if (tid == 0) red[4] = 1.0f / (red[0] + red[1] + red[2] + red[3]);
    __syncthreads();
    const float inv = red[4];
    unsigned short* P = (unsigned short*)Cm;      // bf16 row stride 4096
    us4* Prow = (us4*)(P + (long)i * 4096);
    const int iend4 = (((i >> 7) + 1) << 7) >> 2; // zero-pad to 128-tile edge
    for (int j4 = tid; j4 < iend4; j4 += 256) {
        us4 ov;
#pragma unroll
        for (int e = 0; e < 4; ++e) {
            const int j = j4 * 4 + e;
            const float pv = (j < n) ? s[j] * inv : 0.f;
            ov[e] = f2bf(pv);
        }
        Prow[j4] = ov;
    }
}

// out = P @ V. XCD-aware z clustering + big-K tiles dispatched first.
__global__ __launch_bounds__(256, 3) void pv_kernel(
    const float* __restrict__ C8, const unsigned short* __restrict__ vT,
    float* __restrict__ out)
{
    __shared__ SMem sm;
    EPI_COORDS();
    const long TD = (long)T_ * D_;
    const long DT = (long)D_ * T_;
    f32x16 acc[2][2];
    const int z = blockIdx.x & 7;             // XCD cluster by batch
    const int q = blockIdx.x >> 3;            // 0..63
    const int it = 15 - (q >> 2);             // big K first
    const int jt = q & 3;
    const int i0 = it * 128, j0 = jt * 128;
    const int kmax = i0 + 128;                // causal K-limit (multiple of 128)
    gemm_core((const unsigned short*)(C8 + (long)z * 4194304L) + (long)i0 * 4096, 4096,
              vT + (long)z * DT + (long)j0 * 2048, 2048, kmax, sm, acc);
#pragma unroll
    for (int r2 = 0; r2 < 2; ++r2)
#pragma unroll
        for (int c2 = 0; c2 < 2; ++c2) {
            const int gj = j0 + wn + c2 * 32 + l31;
#pragma unroll
            for (int reg = 0; reg < 16; ++reg) {
                const int rl = (reg & 3) + 8 * (reg >> 2) + 4 * hi;
                const int gi = i0 + wm + r2 * 32 + rl;
                out[(long)z * TD + (long)gi * 512 + gj] = acc[r2][c2][reg];
            }
        }
}

// ---------------------------------------------------------------- launcher
extern "C" void kernel_launch(void* const* d_in, const int* in_sizes, int n_in,
                              void* d_out, int out_size, void* d_ws, size_t ws_size,
                              hipStream_t stream) {
    (void)in_sizes; (void)n_in; (void)out_size; (void)ws_size;
    const float* inputs = (const float*)d_in[0];
    const float* Wq = (const float*)d_in[1];
    const float* Wk = (const float*)d_in[2];
    const float* Wv = (const float*)d_in[3];
    const float* Wrel = (const float*)d_in[4];
    const float* cb = (const float*)d_in[5];
    const float* rb = (const float*)d_in[6];
    float* out = (float*)d_out;

    // workspace layout (~357 MB)
    char* ws = (char*)d_ws;
    unsigned short* in_bf = (unsigned short*)ws;                   // 16384x512
    unsigned short* WqT = (unsigned short*)(ws + 16777216);
    unsigned short* WkT = WqT + 262144;
    unsigned short* WvT = WkT + 262144;
    unsigned short* WrT = WvT + 262144;
    unsigned short* pe  = WrT + 262144;                            // 2048x512
    unsigned short* qc  = pe + 1048576;                            // 16384x512
    unsigned short* qr  = qc + 8388608;
    unsigned short* kbf = qr + 8388608;
    unsigned short* vT  = kbf + 8388608;                           // 8 x 512x2048
    unsigned short* rk  = vT + 8388608;                            // 2048x512
    float* C8 = (float*)(rk + 1048576);                            // 8 x 2048x2048 f32
    float* R8 = C8 + 33554432;                                     // 8 x 2048x2048 f32

    prep_all<<<dim3(10240), 256, 0, stream>>>(inputs, Wq, Wk, Wv, Wrel,
                                              in_bf, WqT, WkT, WvT, WrT, pe);
    proj_kernel<<<dim3(1600), 256, 0, stream>>>(in_bf, WqT, WkT, WvT, WrT, pe, cb, rb,
                                                qc, qr, kbf, vT, rk);
    score_kernel<<<dim3(2176), 256, 0, stream>>>(qc, qr, kbf, rk, C8, R8);
    softmax_kernel<<<dim3(2048, 8), 256, 0, stream>>>(C8, R8);
    pv_kernel<<<dim3(512), 256, 0, stream>>>(C8, vT, out);
}

// Round 3
// 363.584 us; speedup vs baseline: 1.0373x; 1.0373x over previous
//
#include <hip/hip_runtime.h>

typedef __attribute__((ext_vector_type(8))) short short8;
typedef __attribute__((ext_vector_type(4))) float f32x4;
typedef __attribute__((ext_vector_type(4))) float fvec4;
typedef __attribute__((ext_vector_type(4))) unsigned short us4;

#define T_ 2048
#define D_ 512
#define SC_ 0.04419417382415922f   // 1/sqrt(512)

__device__ __forceinline__ unsigned short f2bf(float f) {
    unsigned int u = __float_as_uint(f);
    u += 0x7fffu + ((u >> 16) & 1u);
    return (unsigned short)(u >> 16);
}

// async global->LDS, 16B per lane; LDS dest = wave-uniform base + lane*16
__device__ __forceinline__ void gload16(const void* g, void* l) {
    __builtin_amdgcn_global_load_lds((const __attribute__((address_space(1))) unsigned int*)g,
                                     (__attribute__((address_space(3))) unsigned int*)l,
                                     16, 0, 0);
}

// ---------------------------------------------------------------- merged prep
__global__ __launch_bounds__(256) void prep_all(
    const float* __restrict__ in_f,
    const float* __restrict__ Wq, const float* __restrict__ Wk,
    const float* __restrict__ Wv, const float* __restrict__ Wr,
    unsigned short* __restrict__ in_bf,
    unsigned short* __restrict__ WqT, unsigned short* __restrict__ WkT,
    unsigned short* __restrict__ WvT, unsigned short* __restrict__ WrT,
    unsigned short* __restrict__ pe)
{
    const int bb = blockIdx.x;
    const int tid = threadIdx.x;
    if (bb < 8192) {
        const int idx = bb * 256 + tid;
        fvec4 v = ((const fvec4*)in_f)[idx];
        us4 o;
        o.x = f2bf(v.x); o.y = f2bf(v.y); o.z = f2bf(v.z); o.w = f2bf(v.w);
        ((us4*)in_bf)[idx] = o;
    } else if (bb < 9216) {
        __shared__ float wt[32][33];              // padded: no bank conflicts
        const int t = bb - 8192;                  // 0..1023
        const int w = t >> 8, tile = t & 255;
        const int tr = (tile >> 4) * 32, tc = (tile & 15) * 32;
        const float* W = (w == 0) ? Wq : (w == 1) ? Wk : (w == 2) ? Wv : Wr;
        unsigned short* WT = (w == 0) ? WqT : (w == 1) ? WkT : (w == 2) ? WvT : WrT;
        const int r0 = tid >> 5, c0 = tid & 31;
#pragma unroll
        for (int p = 0; p < 4; ++p)
            wt[r0 + 8 * p][c0] = W[(long)(tr + r0 + 8 * p) * 512 + tc + c0];
        __syncthreads();
#pragma unroll
        for (int p = 0; p < 4; ++p)
            WT[(long)(tc + r0 + 8 * p) * 512 + tr + c0] = f2bf(wt[c0][r0 + 8 * p]);
    } else {
        const int idx = (bb - 9216) * 256 + tid;  // 0..262143 us4 chunks
        const int o = idx * 4;
        const int rpos = o >> 9;
        us4 ov;
#pragma unroll
        for (int e = 0; e < 4; ++e) {
            const int c = (o + e) & 511;
            const int ci = (c < 256) ? c : c - 256;
            const float dv = expf((float)ci * -0.03611898183128701f);  // -log(1e4)/255
            const float ang = (float)rpos * dv;
            ((unsigned short*)&ov)[e] = f2bf((c < 256) ? sinf(ang) : cosf(ang));
        }
        ((us4*)pe)[idx] = ov;
    }
}

// ---------------------------------------------------------------- GEMM core
// BK=64. LDS tile [128][64] bf16 (16 KB each). Element (row,c) lives in 16B
// chunk (row, (c/8) ^ (row&7)) — XOR swizzle: 0 bank conflicts (verified R5/R6).
struct __align__(16) SMem {
    unsigned short At[128 * 64];   // 16 KB
    unsigned short Bt[128 * 64];   // 16 KB
};

__device__ __forceinline__ void gemm_core(const unsigned short* __restrict__ A, long lda,
                                          const unsigned short* __restrict__ B, long ldb,
                                          int kmax, SMem& sm, f32x4 (&acc)[4][4]) {
    const int tid = threadIdx.x;
    const int wid = tid >> 6;
    const int lane = tid & 63;
    const int quad = lane >> 4;
    const int lr = lane & 15;
    const int wm = (wid & 1) * 64;
    const int wn = (wid >> 1) * 64;
#pragma unroll
    for (int r = 0; r < 4; ++r)
#pragma unroll
        for (int c = 0; c < 4; ++c) acc[r][c] = (f32x4){0.f, 0.f, 0.f, 0.f};

    const int sr = tid >> 3;                             // staging row 0..31
    const int l8 = ((tid & 7) ^ (sr & 7)) * 8;           // swizzled source chunk
    const unsigned short* Ag = A + (long)sr * lda + l8;
    const unsigned short* Bg = B + (long)sr * ldb + l8;

    for (int kk = 0; kk < kmax; kk += 64) {
#pragma unroll
        for (int c = 0; c < 4; ++c) {                    // rows 32c..32c+31
            gload16(Ag + (long)(32 * c) * lda + kk, &sm.At[c * 2048 + wid * 512]);
            gload16(Bg + (long)(32 * c) * ldb + kk, &sm.Bt[c * 2048 + wid * 512]);
        }
        __syncthreads();
#pragma unroll
        for (int ks = 0; ks < 2; ++ks) {
            short8 av[4], bv[4];
#pragma unroll
            for (int r = 0; r < 4; ++r) {
                const int row = wm + r * 16 + lr;
                av[r] = *(const short8*)&sm.At[row * 64 + (((ks * 4 + quad) ^ (row & 7)) * 8)];
            }
#pragma unroll
            for (int c = 0; c < 4; ++c) {
                const int row = wn + c * 16 + lr;
                bv[c] = *(const short8*)&sm.Bt[row * 64 + (((ks * 4 + quad) ^ (row & 7)) * 8)];
            }
#pragma unroll
            for (int r = 0; r < 4; ++r)
#pragma unroll
                for (int c = 0; c < 4; ++c)
                    acc[r][c] = __builtin_amdgcn_mfma_f32_16x16x32_bf16(av[r], bv[c], acc[r][c], 0, 0, 0);
        }
        __syncthreads();
    }
}

// C/D layout col=lane&15, row=quad*4+reg  [verified m89/m91]
#define EPI_COORDS()                               \
    const int tid = threadIdx.x;                   \
    const int wid = tid >> 6;                      \
    const int lane = tid & 63;                     \
    const int quad = lane >> 4;                    \
    const int lr = lane & 15;                      \
    const int wm = (wid & 1) * 64;                 \
    const int wn = (wid >> 1) * 64;

// ---------------------------------------------------------------- phase kernels
__global__ __launch_bounds__(256, 3) void proj_kernel(
    const unsigned short* __restrict__ in_bf,
    const unsigned short* __restrict__ WqT, const unsigned short* __restrict__ WkT,
    const unsigned short* __restrict__ WvT, const unsigned short* __restrict__ WrT,
    const unsigned short* __restrict__ pe,
    const float* __restrict__ cb, const float* __restrict__ rb,
    unsigned short* __restrict__ qc, unsigned short* __restrict__ qr,
    unsigned short* __restrict__ kbf, unsigned short* __restrict__ vT,
    unsigned short* __restrict__ rk)
{
    __shared__ SMem sm;
    EPI_COORDS();
    const long TD = (long)T_ * D_;
    const long DT = (long)D_ * T_;
    f32x4 acc[4][4];
    const int t = blockIdx.x;   // 0..1599
    if (t < 1024) {                           // qc/qr (t<512) and k (t<1024)
        const int r = t & 511;
        const int it = r >> 2, jt = r & 3;
        const unsigned short* Bw = (t < 512) ? WqT : WkT;
        gemm_core(in_bf + (long)it * 128 * 512, 512, Bw + (long)jt * 128 * 512, 512, 512, sm, acc);
        const int i0 = it * 128, j0 = jt * 128;
#pragma unroll
        for (int r2 = 0; r2 < 4; ++r2)
#pragma unroll
            for (int c2 = 0; c2 < 4; ++c2) {
                const int gi = i0 + wm + r2 * 16 + quad * 4;
                const int gj = j0 + wn + c2 * 16 + lr;
#pragma unroll
                for (int tt = 0; tt < 4; ++tt) {
                    const float v = acc[r2][c2][tt];
                    const long row = gi + tt;
                    if (t < 512) {
                        qc[row * 512 + gj] = f2bf(v + cb[gj]);
                        qr[row * 512 + gj] = f2bf(v + rb[gj]);
                    } else {
                        kbf[row * 512 + gj] = f2bf(v);
                    }
                }
            }
    } else if (t < 1536) {                    // vT[b] = Wv^T @ in[b]^T
        const int r = t - 1024;
        const int z = r >> 6, rr = r & 63;
        const int it = rr >> 4, jt = rr & 15;
        const int i0 = it * 128, j0 = jt * 128;
        gemm_core(WvT + (long)i0 * 512, 512, in_bf + (long)z * TD + (long)j0 * 512, 512, 512, sm, acc);
#pragma unroll
        for (int r2 = 0; r2 < 4; ++r2)
#pragma unroll
            for (int c2 = 0; c2 < 4; ++c2) {
                const int gi = i0 + wm + r2 * 16 + quad * 4;
                const int gj = j0 + wn + c2 * 16 + lr;
#pragma unroll
                for (int tt = 0; tt < 4; ++tt)
                    vT[(long)z * DT + (long)(gi + tt) * 2048 + gj] = f2bf(acc[r2][c2][tt]);
            }
    } else {                                  // rk = pe @ Wrel
        const int r = t - 1536;
        const int it = r >> 2, jt = r & 3;
        const int i0 = it * 128, j0 = jt * 128;
        gemm_core(pe + (long)i0 * 512, 512, WrT + (long)j0 * 512, 512, 512, sm, acc);
#pragma unroll
        for (int r2 = 0; r2 < 4; ++r2)
#pragma unroll
            for (int c2 = 0; c2 < 4; ++c2) {
                const int gi = i0 + wm + r2 * 16 + quad * 4;
                const int gj = j0 + wn + c2 * 16 + lr;
#pragma unroll
                for (int tt = 0; tt < 4; ++tt)
                    rk[(long)(gi + tt) * 512 + gj] = f2bf(acc[r2][c2][tt]);
            }
    }
}

// content scores -> C8 (pre-scaled, causal tiles) and rel scores -> R8.
// R8 is written SHIFTED and PRE-SCALED: Rs[i][j] = SC * R[i][p], j = p + i - 2047.
// XCD-aware: z = blockIdx & 7 so each XCD works one batch.
__global__ __launch_bounds__(256, 3) void score_kernel(
    const unsigned short* __restrict__ qc, const unsigned short* __restrict__ qr,
    const unsigned short* __restrict__ kbf, const unsigned short* __restrict__ rk,
    float* __restrict__ C8, float* __restrict__ R8)
{
    __shared__ SMem sm;
    EPI_COORDS();
    const long TD = (long)T_ * D_;
    f32x4 acc[4][4];
    const int z = blockIdx.x & 7;             // XCD cluster by batch
    const int rr = blockIdx.x >> 3;           // 0..271
    if (rr < 136) {
        const int r = rr;
        int a = (int)((sqrtf(8.f * (float)r + 1.f) - 1.f) * 0.5f);
        if ((a + 1) * (a + 2) / 2 <= r) ++a;
        if (a * (a + 1) / 2 > r) --a;
        const int b = r - a * (a + 1) / 2;    // b <= a (causal tiles)
        const int i0 = a * 128, j0 = b * 128;
        gemm_core(qc + (long)z * TD + (long)i0 * 512, 512,
                  kbf + (long)z * TD + (long)j0 * 512, 512, 512, sm, acc);
        float* Cf = C8 + (long)z * 4194304L;
#pragma unroll
        for (int r2 = 0; r2 < 4; ++r2)
#pragma unroll
            for (int c2 = 0; c2 < 4; ++c2) {
                const int gi = i0 + wm + r2 * 16 + quad * 4;
                const int gj = j0 + wn + c2 * 16 + lr;
#pragma unroll
                for (int tt = 0; tt < 4; ++tt)
                    Cf[(long)(gi + tt) * 2048 + gj] = acc[r2][c2][tt] * SC_;
            }
    } else {
        const int r = rr - 136;
        int u = (int)((sqrtf(8.f * (float)r + 1.f) - 1.f) * 0.5f);
        if ((u + 1) * (u + 2) / 2 <= r) ++u;
        if (u * (u + 1) / 2 > r) --u;
        const int v2 = r - u * (u + 1) / 2;   // v2 <= u
        const int a = u, b = 15 - u + v2;     // tiles covering p >= T-1-i
        const int i0 = a * 128, p0 = b * 128;
        gemm_core(qr + (long)z * TD + (long)i0 * 512, 512,
                  rk + (long)p0 * 512, 512, 512, sm, acc);
        float* Rf = R8 + (long)z * 4194304L;
#pragma unroll
        for (int r2 = 0; r2 < 4; ++r2)
#pragma unroll
            for (int c2 = 0; c2 < 4; ++c2) {
                const int gi = i0 + wm + r2 * 16 + quad * 4;
                const int gp = p0 + wn + c2 * 16 + lr;
#pragma unroll
                for (int tt = 0; tt < 4; ++tt) {
                    const int row = gi + tt;
                    const int j = gp + row - 2047;       // shifted column
                    if (j >= 0)
                        Rf[(long)row * 2048 + j] = acc[r2][c2][tt] * SC_;
                }
            }
    }
}

// row softmax: S[i,j] = C8[i,j] + Rs[i,j] (both pre-scaled, row-aligned).
// One row per block, grid (2048, 8). float4 loads, us4 stores.
__global__ __launch_bounds__(256) void softmax_kernel(float* __restrict__ C8,
                                                      const float* __restrict__ R8) {
    const int i = blockIdx.x;
    float* Cm = C8 + (long)blockIdx.y * 4194304L;
    const float* Rm = R8 + (long)blockIdx.y * 4194304L;
    __shared__ float s[2048];
    __shared__ float red[5];
    const int tid = threadIdx.x;
    const int wid = tid >> 6;
    const int n = i + 1;
    const int n4 = (n + 3) >> 2;
    const f32x4* c4 = (const f32x4*)(Cm + (long)i * 2048);
    const f32x4* r4 = (const f32x4*)(Rm + (long)i * 2048);
    float lmax = -3.0e38f;
    for (int j4 = tid; j4 < n4; j4 += 256) {
        const f32x4 c = c4[j4];
        const f32x4 r = r4[j4];
        f32x4 v;
#pragma unroll
        for (int e = 0; e < 4; ++e) {
            const int j = j4 * 4 + e;
            const float vv = (j < n) ? c[e] + r[e] : -3.0e38f;   // mask tail/poison
            v[e] = vv;
            lmax = fmaxf(lmax, vv);
        }
        *(f32x4*)&s[j4 * 4] = v;
    }
    for (int o = 32; o; o >>= 1) lmax = fmaxf(lmax, __shfl_down(lmax, o));
    if ((tid & 63) == 0) red[wid] = lmax;
    __syncthreads();
    if (tid == 0) red[4] = fmaxf(fmaxf(red[0], red[1]), fmaxf(red[2], red[3]));
    __syncthreads();
    const float m = red[4];
    float lsum = 0.f;
    for (int j4 = tid; j4 < n4; j4 += 256) {
        f32x4 v = *(f32x4*)&s[j4 * 4];
#pragma unroll
        for (int e = 0; e < 4; ++e) {
            const float x = __expf(v[e] - m);      // masked lanes -> exp(-inf)=0
            v[e] = x;
            lsum += x;
        }
        *(f32x4*)&s[j4 * 4] = v;
    }
    for (int o = 32; o; o >>= 1) lsum += __shfl_down(lsum, o);
    if ((tid & 63) == 0) red[wid] = lsum;
    __syncthreads();
    if (tid == 0) red[4] = 1.0f / (red[0] + red[1] + red[2] + red[3]);
    __syncthreads();
    const float inv = red[4];
    unsigned short* P = (unsigned short*)Cm;      // bf16 row stride 4096
    us4* Prow = (us4*)(P + (long)i * 4096);
    const int iend4 = (((i >> 7) + 1) << 7) >> 2; // zero-pad to 128-tile edge
    for (int j4 = tid; j4 < iend4; j4 += 256) {
        us4 ov;
#pragma unroll
        for (int e = 0; e < 4; ++e) {
            const int j = j4 * 4 + e;
            const float pv = (j < n) ? s[j] * inv : 0.f;
            ov[e] = f2bf(pv);
        }
        Prow[j4] = ov;
    }
}

// out = P @ V. XCD-aware z clustering. All 512 blocks are co-resident
// (2/CU), so dispatch ORDER doesn't balance — PAIRING does: block c pairs
// with c+256 on the same CU; map it so paired K-sums are constant:
// q<32 -> it=15-(q>>2) (K=2048..1152), q>=32 -> it=(q>>2)-8 (K=128..1024).
// Every CU then gets 17 work-units instead of worst-case 24.
__global__ __launch_bounds__(256, 3) void pv_kernel(
    const float* __restrict__ C8, const unsigned short* __restrict__ vT,
    float* __restrict__ out)
{
    __shared__ SMem sm;
    EPI_COORDS();
    const long TD = (long)T_ * D_;
    const long DT = (long)D_ * T_;
    f32x4 acc[4][4];
    const int z = blockIdx.x & 7;             // XCD cluster by batch
    const int q = blockIdx.x >> 3;            // 0..63
    const int s4 = q >> 2;                    // 0..15
    const int it = (q < 32) ? (15 - s4) : (s4 - 8);
    const int jt = q & 3;
    const int i0 = it * 128, j0 = jt * 128;
    const int kmax = i0 + 128;                // causal K-limit (multiple of 128)
    gemm_core((const unsigned short*)(C8 + (long)z * 4194304L) + (long)i0 * 4096, 4096,
              vT + (long)z * DT + (long)j0 * 2048, 2048, kmax, sm, acc);
#pragma unroll
    for (int r2 = 0; r2 < 4; ++r2)
#pragma unroll
        for (int c2 = 0; c2 < 4; ++c2) {
            const int gi = i0 + wm + r2 * 16 + quad * 4;
            const int gj = j0 + wn + c2 * 16 + lr;
#pragma unroll
            for (int tt = 0; tt < 4; ++tt)
                out[(long)z * TD + (long)(gi + tt) * 512 + gj] = acc[r2][c2][tt];
        }
}

// ---------------------------------------------------------------- launcher
extern "C" void kernel_launch(void* const* d_in, const int* in_sizes, int n_in,
                              void* d_out, int out_size, void* d_ws, size_t ws_size,
                              hipStream_t stream) {
    (void)in_sizes; (void)n_in; (void)out_size; (void)ws_size;
    const float* inputs = (const float*)d_in[0];
    const float* Wq = (const float*)d_in[1];
    const float* Wk = (const float*)d_in[2];
    const float* Wv = (const float*)d_in[3];
    const float* Wrel = (const float*)d_in[4];
    const float* cb = (const float*)d_in[5];
    const float* rb = (const float*)d_in[6];
    float* out = (float*)d_out;

    // workspace layout (~357 MB)
    char* ws = (char*)d_ws;
    unsigned short* in_bf = (unsigned short*)ws;                   // 16384x512
    unsigned short* WqT = (unsigned short*)(ws + 16777216);
    unsigned short* WkT = WqT + 262144;
    unsigned short* WvT = WkT + 262144;
    unsigned short* WrT = WvT + 262144;
    unsigned short* pe  = WrT + 262144;                            // 2048x512
    unsigned short* qc  = pe + 1048576;                            // 16384x512
    unsigned short* qr  = qc + 8388608;
    unsigned short* kbf = qr + 8388608;
    unsigned short* vT  = kbf + 8388608;                           // 8 x 512x2048
    unsigned short* rk  = vT + 8388608;                            // 2048x512
    float* C8 = (float*)(rk + 1048576);                            // 8 x 2048x2048 f32
    float* R8 = C8 + 33554432;                                     // 8 x 2048x2048 f32

    prep_all<<<dim3(10240), 256, 0, stream>>>(inputs, Wq, Wk, Wv, Wrel,
                                              in_bf, WqT, WkT, WvT, WrT, pe);
    proj_kernel<<<dim3(1600), 256, 0, stream>>>(in_bf, WqT, WkT, WvT, WrT, pe, cb, rb,
                                                qc, qr, kbf, vT, rk);
    score_kernel<<<dim3(2176), 256, 0, stream>>>(qc, qr, kbf, rk, C8, R8);
    softmax_kernel<<<dim3(2048, 8), 256, 0, stream>>>(C8, R8);
    pv_kernel<<<dim3(512), 256, 0, stream>>>(C8, vT, out);
}

// Round 4
// 347.974 us; speedup vs baseline: 1.0838x; 1.0449x over previous
//
#include <hip/hip_runtime.h>

typedef __attribute__((ext_vector_type(8))) short short8;
typedef __attribute__((ext_vector_type(4))) float f32x4;
typedef __attribute__((ext_vector_type(4))) float fvec4;
typedef __attribute__((ext_vector_type(4))) unsigned short us4;

#define T_ 2048
#define D_ 512
#define SC_ 0.04419417382415922f   // 1/sqrt(512)

__device__ __forceinline__ unsigned short f2bf(float f) {
    unsigned int u = __float_as_uint(f);
    u += 0x7fffu + ((u >> 16) & 1u);
    return (unsigned short)(u >> 16);
}

__device__ __forceinline__ float bf2f(unsigned short b) {
    return __uint_as_float((unsigned int)b << 16);
}

// async global->LDS, 16B per lane; LDS dest = wave-uniform base + lane*16
__device__ __forceinline__ void gload16(const void* g, void* l) {
    __builtin_amdgcn_global_load_lds((const __attribute__((address_space(1))) unsigned int*)g,
                                     (__attribute__((address_space(3))) unsigned int*)l,
                                     16, 0, 0);
}

// ---------------------------------------------------------------- merged prep
__global__ __launch_bounds__(256) void prep_all(
    const float* __restrict__ in_f,
    const float* __restrict__ Wq, const float* __restrict__ Wk,
    const float* __restrict__ Wv, const float* __restrict__ Wr,
    unsigned short* __restrict__ in_bf,
    unsigned short* __restrict__ WqT, unsigned short* __restrict__ WkT,
    unsigned short* __restrict__ WvT, unsigned short* __restrict__ WrT,
    unsigned short* __restrict__ pe)
{
    const int bb = blockIdx.x;
    const int tid = threadIdx.x;
    if (bb < 8192) {
        const int idx = bb * 256 + tid;
        fvec4 v = ((const fvec4*)in_f)[idx];
        us4 o;
        o.x = f2bf(v.x); o.y = f2bf(v.y); o.z = f2bf(v.z); o.w = f2bf(v.w);
        ((us4*)in_bf)[idx] = o;
    } else if (bb < 9216) {
        __shared__ float wt[32][33];              // padded: no bank conflicts
        const int t = bb - 8192;                  // 0..1023
        const int w = t >> 8, tile = t & 255;
        const int tr = (tile >> 4) * 32, tc = (tile & 15) * 32;
        const float* W = (w == 0) ? Wq : (w == 1) ? Wk : (w == 2) ? Wv : Wr;
        unsigned short* WT = (w == 0) ? WqT : (w == 1) ? WkT : (w == 2) ? WvT : WrT;
        const int r0 = tid >> 5, c0 = tid & 31;
#pragma unroll
        for (int p = 0; p < 4; ++p)
            wt[r0 + 8 * p][c0] = W[(long)(tr + r0 + 8 * p) * 512 + tc + c0];
        __syncthreads();
#pragma unroll
        for (int p = 0; p < 4; ++p)
            WT[(long)(tc + r0 + 8 * p) * 512 + tr + c0] = f2bf(wt[c0][r0 + 8 * p]);
    } else {
        const int idx = (bb - 9216) * 256 + tid;  // 0..262143 us4 chunks
        const int o = idx * 4;
        const int rpos = o >> 9;
        us4 ov;
#pragma unroll
        for (int e = 0; e < 4; ++e) {
            const int c = (o + e) & 511;
            const int ci = (c < 256) ? c : c - 256;
            const float dv = expf((float)ci * -0.03611898183128701f);  // -log(1e4)/255
            const float ang = (float)rpos * dv;
            ((unsigned short*)&ov)[e] = f2bf((c < 256) ? sinf(ang) : cosf(ang));
        }
        ((us4*)pe)[idx] = ov;
    }
}

// ---------------------------------------------------------------- GEMM core
// BK=64. LDS tile [128][64] bf16 (16 KB each). Element (row,c) lives in 16B
// chunk (row, (c/8) ^ (row&7)) — XOR swizzle: 0 bank conflicts (verified R5/R6).
struct __align__(16) SMem {
    unsigned short At[128 * 64];   // 16 KB
    unsigned short Bt[128 * 64];   // 16 KB
};

__device__ __forceinline__ void gemm_core(const unsigned short* __restrict__ A, long lda,
                                          const unsigned short* __restrict__ B, long ldb,
                                          int kmax, SMem& sm, f32x4 (&acc)[4][4]) {
    const int tid = threadIdx.x;
    const int wid = tid >> 6;
    const int lane = tid & 63;
    const int quad = lane >> 4;
    const int lr = lane & 15;
    const int wm = (wid & 1) * 64;
    const int wn = (wid >> 1) * 64;
#pragma unroll
    for (int r = 0; r < 4; ++r)
#pragma unroll
        for (int c = 0; c < 4; ++c) acc[r][c] = (f32x4){0.f, 0.f, 0.f, 0.f};

    const int sr = tid >> 3;                             // staging row 0..31
    const int l8 = ((tid & 7) ^ (sr & 7)) * 8;           // swizzled source chunk
    const unsigned short* Ag = A + (long)sr * lda + l8;
    const unsigned short* Bg = B + (long)sr * ldb + l8;

    for (int kk = 0; kk < kmax; kk += 64) {
#pragma unroll
        for (int c = 0; c < 4; ++c) {                    // rows 32c..32c+31
            gload16(Ag + (long)(32 * c) * lda + kk, &sm.At[c * 2048 + wid * 512]);
            gload16(Bg + (long)(32 * c) * ldb + kk, &sm.Bt[c * 2048 + wid * 512]);
        }
        __syncthreads();
#pragma unroll
        for (int ks = 0; ks < 2; ++ks) {
            short8 av[4], bv[4];
#pragma unroll
            for (int r = 0; r < 4; ++r) {
                const int row = wm + r * 16 + lr;
                av[r] = *(const short8*)&sm.At[row * 64 + (((ks * 4 + quad) ^ (row & 7)) * 8)];
            }
#pragma unroll
            for (int c = 0; c < 4; ++c) {
                const int row = wn + c * 16 + lr;
                bv[c] = *(const short8*)&sm.Bt[row * 64 + (((ks * 4 + quad) ^ (row & 7)) * 8)];
            }
#pragma unroll
            for (int r = 0; r < 4; ++r)
#pragma unroll
                for (int c = 0; c < 4; ++c)
                    acc[r][c] = __builtin_amdgcn_mfma_f32_16x16x32_bf16(av[r], bv[c], acc[r][c], 0, 0, 0);
        }
        __syncthreads();
    }
}

// C/D layout col=lane&15, row=quad*4+reg  [verified m89/m91]
#define EPI_COORDS()                               \
    const int tid = threadIdx.x;                   \
    const int wid = tid >> 6;                      \
    const int lane = tid & 63;                     \
    const int quad = lane >> 4;                    \
    const int lr = lane & 15;                      \
    const int wm = (wid & 1) * 64;                 \
    const int wn = (wid >> 1) * 64;

// ---------------------------------------------------------------- phase kernels
__global__ __launch_bounds__(256, 3) void proj_kernel(
    const unsigned short* __restrict__ in_bf,
    const unsigned short* __restrict__ WqT, const unsigned short* __restrict__ WkT,
    const unsigned short* __restrict__ WvT, const unsigned short* __restrict__ WrT,
    const unsigned short* __restrict__ pe,
    const float* __restrict__ cb, const float* __restrict__ rb,
    unsigned short* __restrict__ qc, unsigned short* __restrict__ qr,
    unsigned short* __restrict__ kbf, unsigned short* __restrict__ vT,
    unsigned short* __restrict__ rk)
{
    __shared__ SMem sm;
    EPI_COORDS();
    const long TD = (long)T_ * D_;
    const long DT = (long)D_ * T_;
    f32x4 acc[4][4];
    const int t = blockIdx.x;   // 0..1599
    if (t < 1024) {                           // qc/qr (t<512) and k (t<1024)
        const int r = t & 511;
        const int it = r >> 2, jt = r & 3;
        const unsigned short* Bw = (t < 512) ? WqT : WkT;
        gemm_core(in_bf + (long)it * 128 * 512, 512, Bw + (long)jt * 128 * 512, 512, 512, sm, acc);
        const int i0 = it * 128, j0 = jt * 128;
#pragma unroll
        for (int r2 = 0; r2 < 4; ++r2)
#pragma unroll
            for (int c2 = 0; c2 < 4; ++c2) {
                const int gi = i0 + wm + r2 * 16 + quad * 4;
                const int gj = j0 + wn + c2 * 16 + lr;
#pragma unroll
                for (int tt = 0; tt < 4; ++tt) {
                    const float v = acc[r2][c2][tt];
                    const long row = gi + tt;
                    if (t < 512) {
                        qc[row * 512 + gj] = f2bf(v + cb[gj]);
                        qr[row * 512 + gj] = f2bf(v + rb[gj]);
                    } else {
                        kbf[row * 512 + gj] = f2bf(v);
                    }
                }
            }
    } else if (t < 1536) {                    // vT[b] = Wv^T @ in[b]^T
        const int r = t - 1024;
        const int z = r >> 6, rr = r & 63;
        const int it = rr >> 4, jt = rr & 15;
        const int i0 = it * 128, j0 = jt * 128;
        gemm_core(WvT + (long)i0 * 512, 512, in_bf + (long)z * TD + (long)j0 * 512, 512, 512, sm, acc);
#pragma unroll
        for (int r2 = 0; r2 < 4; ++r2)
#pragma unroll
            for (int c2 = 0; c2 < 4; ++c2) {
                const int gi = i0 + wm + r2 * 16 + quad * 4;
                const int gj = j0 + wn + c2 * 16 + lr;
#pragma unroll
                for (int tt = 0; tt < 4; ++tt)
                    vT[(long)z * DT + (long)(gi + tt) * 2048 + gj] = f2bf(acc[r2][c2][tt]);
            }
    } else {                                  // rk = pe @ Wrel
        const int r = t - 1536;
        const int it = r >> 2, jt = r & 3;
        const int i0 = it * 128, j0 = jt * 128;
        gemm_core(pe + (long)i0 * 512, 512, WrT + (long)j0 * 512, 512, 512, sm, acc);
#pragma unroll
        for (int r2 = 0; r2 < 4; ++r2)
#pragma unroll
            for (int c2 = 0; c2 < 4; ++c2) {
                const int gi = i0 + wm + r2 * 16 + quad * 4;
                const int gj = j0 + wn + c2 * 16 + lr;
#pragma unroll
                for (int tt = 0; tt < 4; ++tt)
                    rk[(long)(gi + tt) * 512 + gj] = f2bf(acc[r2][c2][tt]);
            }
    }
}

// content scores -> C8 (f32, pre-scaled, causal tiles) and rel scores -> R8b
// (bf16!). R8b is SHIFTED and PRE-SCALED: Rs[i][j] = bf16(SC * R[i][p]),
// j = p + i - 2047. bf16 rel logits (std~1, |max|~3.5) add <=0.007 logit
// error — same order as the existing P-bf16 rounding. Halves R traffic.
// XCD-aware: z = blockIdx & 7 so each XCD works one batch.
__global__ __launch_bounds__(256, 3) void score_kernel(
    const unsigned short* __restrict__ qc, const unsigned short* __restrict__ qr,
    const unsigned short* __restrict__ kbf, const unsigned short* __restrict__ rk,
    float* __restrict__ C8, unsigned short* __restrict__ R8b)
{
    __shared__ SMem sm;
    EPI_COORDS();
    const long TD = (long)T_ * D_;
    f32x4 acc[4][4];
    const int z = blockIdx.x & 7;             // XCD cluster by batch
    const int rr = blockIdx.x >> 3;           // 0..271
    if (rr < 136) {
        const int r = rr;
        int a = (int)((sqrtf(8.f * (float)r + 1.f) - 1.f) * 0.5f);
        if ((a + 1) * (a + 2) / 2 <= r) ++a;
        if (a * (a + 1) / 2 > r) --a;
        const int b = r - a * (a + 1) / 2;    // b <= a (causal tiles)
        const int i0 = a * 128, j0 = b * 128;
        gemm_core(qc + (long)z * TD + (long)i0 * 512, 512,
                  kbf + (long)z * TD + (long)j0 * 512, 512, 512, sm, acc);
        float* Cf = C8 + (long)z * 4194304L;
#pragma unroll
        for (int r2 = 0; r2 < 4; ++r2)
#pragma unroll
            for (int c2 = 0; c2 < 4; ++c2) {
                const int gi = i0 + wm + r2 * 16 + quad * 4;
                const int gj = j0 + wn + c2 * 16 + lr;
#pragma unroll
                for (int tt = 0; tt < 4; ++tt)
                    Cf[(long)(gi + tt) * 2048 + gj] = acc[r2][c2][tt] * SC_;
            }
    } else {
        const int r = rr - 136;
        int u = (int)((sqrtf(8.f * (float)r + 1.f) - 1.f) * 0.5f);
        if ((u + 1) * (u + 2) / 2 <= r) ++u;
        if (u * (u + 1) / 2 > r) --u;
        const int v2 = r - u * (u + 1) / 2;   // v2 <= u
        const int a = u, b = 15 - u + v2;     // tiles covering p >= T-1-i
        const int i0 = a * 128, p0 = b * 128;
        gemm_core(qr + (long)z * TD + (long)i0 * 512, 512,
                  rk + (long)p0 * 512, 512, 512, sm, acc);
        unsigned short* Rb = R8b + (long)z * 4194304L;
#pragma unroll
        for (int r2 = 0; r2 < 4; ++r2)
#pragma unroll
            for (int c2 = 0; c2 < 4; ++c2) {
                const int gi = i0 + wm + r2 * 16 + quad * 4;
                const int gp = p0 + wn + c2 * 16 + lr;
#pragma unroll
                for (int tt = 0; tt < 4; ++tt) {
                    const int row = gi + tt;
                    const int j = gp + row - 2047;       // shifted column
                    if (j >= 0)
                        Rb[(long)row * 2048 + j] = f2bf(acc[r2][c2][tt] * SC_);
                }
            }
    }
}

// row softmax: S[i,j] = C8[i,j] + bf2f(R8b[i,j]) (both pre-scaled, row-aligned).
// One row per block, grid (2048, 8). float4 + us4 loads, us4 stores.
__global__ __launch_bounds__(256) void softmax_kernel(float* __restrict__ C8,
                                                      const unsigned short* __restrict__ R8b) {
    const int i = blockIdx.x;
    float* Cm = C8 + (long)blockIdx.y * 4194304L;
    const unsigned short* Rm = R8b + (long)blockIdx.y * 4194304L;
    __shared__ float s[2048];
    __shared__ float red[5];
    const int tid = threadIdx.x;
    const int wid = tid >> 6;
    const int n = i + 1;
    const int n4 = (n + 3) >> 2;
    const f32x4* c4 = (const f32x4*)(Cm + (long)i * 2048);
    const us4* r4 = (const us4*)(Rm + (long)i * 2048);
    float lmax = -3.0e38f;
    for (int j4 = tid; j4 < n4; j4 += 256) {
        const f32x4 c = c4[j4];
        const us4 r = r4[j4];
        f32x4 v;
#pragma unroll
        for (int e = 0; e < 4; ++e) {
            const int j = j4 * 4 + e;
            const float vv = (j < n) ? c[e] + bf2f(r[e]) : -3.0e38f;  // mask tail/poison
            v[e] = vv;
            lmax = fmaxf(lmax, vv);
        }
        *(f32x4*)&s[j4 * 4] = v;
    }
    for (int o = 32; o; o >>= 1) lmax = fmaxf(lmax, __shfl_down(lmax, o));
    if ((tid & 63) == 0) red[wid] = lmax;
    __syncthreads();
    if (tid == 0) red[4] = fmaxf(fmaxf(red[0], red[1]), fmaxf(red[2], red[3]));
    __syncthreads();
    const float m = red[4];
    float lsum = 0.f;
    for (int j4 = tid; j4 < n4; j4 += 256) {
        f32x4 v = *(f32x4*)&s[j4 * 4];
#pragma unroll
        for (int e = 0; e < 4; ++e) {
            const float x = __expf(v[e] - m);      // masked lanes -> exp(-inf)=0
            v[e] = x;
            lsum += x;
        }
        *(f32x4*)&s[j4 * 4] = v;
    }
    for (int o = 32; o; o >>= 1) lsum += __shfl_down(lsum, o);
    if ((tid & 63) == 0) red[wid] = lsum;
    __syncthreads();
    if (tid == 0) red[4] = 1.0f / (red[0] + red[1] + red[2] + red[3]);
    __syncthreads();
    const float inv = red[4];
    unsigned short* P = (unsigned short*)Cm;      // bf16 row stride 4096
    us4* Prow = (us4*)(P + (long)i * 4096);
    const int iend4 = (((i >> 7) + 1) << 7) >> 2; // zero-pad to 128-tile edge
    for (int j4 = tid; j4 < iend4; j4 += 256) {
        us4 ov;
#pragma unroll
        for (int e = 0; e < 4; ++e) {
            const int j = j4 * 4 + e;
            const float pv = (j < n) ? s[j] * inv : 0.f;
            ov[e] = f2bf(pv);
        }
        Prow[j4] = ov;
    }
}

// out = P @ V. XCD-aware z clustering. All 512 blocks are co-resident
// (2/CU), so dispatch ORDER doesn't balance — PAIRING does: block c pairs
// with c+256 on the same CU; map it so paired K-sums are constant:
// q<32 -> it=15-(q>>2) (K=2048..1152), q>=32 -> it=(q>>2)-8 (K=128..1024).
// Every CU then gets 17 work-units instead of worst-case 24.
__global__ __launch_bounds__(256, 3) void pv_kernel(
    const float* __restrict__ C8, const unsigned short* __restrict__ vT,
    float* __restrict__ out)
{
    __shared__ SMem sm;
    EPI_COORDS();
    const long TD = (long)T_ * D_;
    const long DT = (long)D_ * T_;
    f32x4 acc[4][4];
    const int z = blockIdx.x & 7;             // XCD cluster by batch
    const int q = blockIdx.x >> 3;            // 0..63
    const int s4 = q >> 2;                    // 0..15
    const int it = (q < 32) ? (15 - s4) : (s4 - 8);
    const int jt = q & 3;
    const int i0 = it * 128, j0 = jt * 128;
    const int kmax = i0 + 128;                // causal K-limit (multiple of 128)
    gemm_core((const unsigned short*)(C8 + (long)z * 4194304L) + (long)i0 * 4096, 4096,
              vT + (long)z * DT + (long)j0 * 2048, 2048, kmax, sm, acc);
#pragma unroll
    for (int r2 = 0; r2 < 4; ++r2)
#pragma unroll
        for (int c2 = 0; c2 < 4; ++c2) {
            const int gi = i0 + wm + r2 * 16 + quad * 4;
            const int gj = j0 + wn + c2 * 16 + lr;
#pragma unroll
            for (int tt = 0; tt < 4; ++tt)
                out[(long)z * TD + (long)(gi + tt) * 512 + gj] = acc[r2][c2][tt];
        }
}

// ---------------------------------------------------------------- launcher
extern "C" void kernel_launch(void* const* d_in, const int* in_sizes, int n_in,
                              void* d_out, int out_size, void* d_ws, size_t ws_size,
                              hipStream_t stream) {
    (void)in_sizes; (void)n_in; (void)out_size; (void)ws_size;
    const float* inputs = (const float*)d_in[0];
    const float* Wq = (const float*)d_in[1];
    const float* Wk = (const float*)d_in[2];
    const float* Wv = (const float*)d_in[3];
    const float* Wrel = (const float*)d_in[4];
    const float* cb = (const float*)d_in[5];
    const float* rb = (const float*)d_in[6];
    float* out = (float*)d_out;

    // workspace layout (~290 MB)
    char* ws = (char*)d_ws;
    unsigned short* in_bf = (unsigned short*)ws;                   // 16384x512
    unsigned short* WqT = (unsigned short*)(ws + 16777216);
    unsigned short* WkT = WqT + 262144;
    unsigned short* WvT = WkT + 262144;
    unsigned short* WrT = WvT + 262144;
    unsigned short* pe  = WrT + 262144;                            // 2048x512
    unsigned short* qc  = pe + 1048576;                            // 16384x512
    unsigned short* qr  = qc + 8388608;
    unsigned short* kbf = qr + 8388608;
    unsigned short* vT  = kbf + 8388608;                           // 8 x 512x2048
    unsigned short* rk  = vT + 8388608;                            // 2048x512
    float* C8 = (float*)(rk + 1048576);                            // 8 x 2048x2048 f32
    unsigned short* R8b = (unsigned short*)(C8 + 33554432);        // 8 x 2048x2048 bf16

    prep_all<<<dim3(10240), 256, 0, stream>>>(inputs, Wq, Wk, Wv, Wrel,
                                              in_bf, WqT, WkT, WvT, WrT, pe);
    proj_kernel<<<dim3(1600), 256, 0, stream>>>(in_bf, WqT, WkT, WvT, WrT, pe, cb, rb,
                                                qc, qr, kbf, vT, rk);
    score_kernel<<<dim3(2176), 256, 0, stream>>>(qc, qr, kbf, rk, C8, R8b);
    softmax_kernel<<<dim3(2048, 8), 256, 0, stream>>>(C8, R8b);
    pv_kernel<<<dim3(512), 256, 0, stream>>>(C8, vT, out);
}

// Round 5
// 335.855 us; speedup vs baseline: 1.1229x; 1.0361x over previous
//
#include <hip/hip_runtime.h>

typedef __attribute__((ext_vector_type(8))) short short8;
typedef __attribute__((ext_vector_type(4))) float f32x4;
typedef __attribute__((ext_vector_type(4))) float fvec4;
typedef __attribute__((ext_vector_type(4))) unsigned short us4;

#define T_ 2048
#define D_ 512
#define SC_ 0.04419417382415922f   // 1/sqrt(512)

__device__ __forceinline__ unsigned short f2bf(float f) {
    unsigned int u = __float_as_uint(f);
    u += 0x7fffu + ((u >> 16) & 1u);
    return (unsigned short)(u >> 16);
}

__device__ __forceinline__ float bf2f(unsigned short b) {
    return __uint_as_float((unsigned int)b << 16);
}

// async global->LDS, 16B per lane; LDS dest = wave-uniform base + lane*16
__device__ __forceinline__ void gload16(const void* g, void* l) {
    __builtin_amdgcn_global_load_lds((const __attribute__((address_space(1))) unsigned int*)g,
                                     (__attribute__((address_space(3))) unsigned int*)l,
                                     16, 0, 0);
}

// ---------------------------------------------------------------- merged prep
__global__ __launch_bounds__(256) void prep_all(
    const float* __restrict__ in_f,
    const float* __restrict__ Wq, const float* __restrict__ Wk,
    const float* __restrict__ Wv, const float* __restrict__ Wr,
    unsigned short* __restrict__ in_bf,
    unsigned short* __restrict__ WqT, unsigned short* __restrict__ WkT,
    unsigned short* __restrict__ WvT, unsigned short* __restrict__ WrT,
    unsigned short* __restrict__ pe)
{
    const int bb = blockIdx.x;
    const int tid = threadIdx.x;
    if (bb < 8192) {
        const int idx = bb * 256 + tid;
        fvec4 v = ((const fvec4*)in_f)[idx];
        us4 o;
        o.x = f2bf(v.x); o.y = f2bf(v.y); o.z = f2bf(v.z); o.w = f2bf(v.w);
        ((us4*)in_bf)[idx] = o;
    } else if (bb < 9216) {
        __shared__ float wt[32][33];              // padded: no bank conflicts
        const int t = bb - 8192;                  // 0..1023
        const int w = t >> 8, tile = t & 255;
        const int tr = (tile >> 4) * 32, tc = (tile & 15) * 32;
        const float* W = (w == 0) ? Wq : (w == 1) ? Wk : (w == 2) ? Wv : Wr;
        unsigned short* WT = (w == 0) ? WqT : (w == 1) ? WkT : (w == 2) ? WvT : WrT;
        const int r0 = tid >> 5, c0 = tid & 31;
#pragma unroll
        for (int p = 0; p < 4; ++p)
            wt[r0 + 8 * p][c0] = W[(long)(tr + r0 + 8 * p) * 512 + tc + c0];
        __syncthreads();
#pragma unroll
        for (int p = 0; p < 4; ++p)
            WT[(long)(tc + r0 + 8 * p) * 512 + tr + c0] = f2bf(wt[c0][r0 + 8 * p]);
    } else {
        const int idx = (bb - 9216) * 256 + tid;  // 0..262143 us4 chunks
        const int o = idx * 4;
        const int rpos = o >> 9;
        us4 ov;
#pragma unroll
        for (int e = 0; e < 4; ++e) {
            const int c = (o + e) & 511;
            const int ci = (c < 256) ? c : c - 256;
            const float dv = expf((float)ci * -0.03611898183128701f);  // -log(1e4)/255
            const float ang = (float)rpos * dv;
            ((unsigned short*)&ov)[e] = f2bf((c < 256) ? sinf(ang) : cosf(ang));
        }
        ((us4*)pe)[idx] = ov;
    }
}

// ---------------------------------------------------------------- GEMM core
// BK=64. LDS tile [128][64] bf16 (16 KB each). Element (row,c) lives in 16B
// chunk (row, (c/8) ^ (row&7)) — XOR swizzle: 0 bank conflicts (verified R5/R6).
struct __align__(16) SMem {
    unsigned short At[128 * 64];   // 16 KB
    unsigned short Bt[128 * 64];   // 16 KB
};

__device__ __forceinline__ void gemm_core(const unsigned short* __restrict__ A, long lda,
                                          const unsigned short* __restrict__ B, long ldb,
                                          int kmax, SMem& sm, f32x4 (&acc)[4][4]) {
    const int tid = threadIdx.x;
    const int wid = tid >> 6;
    const int lane = tid & 63;
    const int quad = lane >> 4;
    const int lr = lane & 15;
    const int wm = (wid & 1) * 64;
    const int wn = (wid >> 1) * 64;
#pragma unroll
    for (int r = 0; r < 4; ++r)
#pragma unroll
        for (int c = 0; c < 4; ++c) acc[r][c] = (f32x4){0.f, 0.f, 0.f, 0.f};

    const int sr = tid >> 3;                             // staging row 0..31
    const int l8 = ((tid & 7) ^ (sr & 7)) * 8;           // swizzled source chunk
    const unsigned short* Ag = A + (long)sr * lda + l8;
    const unsigned short* Bg = B + (long)sr * ldb + l8;

    for (int kk = 0; kk < kmax; kk += 64) {
#pragma unroll
        for (int c = 0; c < 4; ++c) {                    // rows 32c..32c+31
            gload16(Ag + (long)(32 * c) * lda + kk, &sm.At[c * 2048 + wid * 512]);
            gload16(Bg + (long)(32 * c) * ldb + kk, &sm.Bt[c * 2048 + wid * 512]);
        }
        __syncthreads();
#pragma unroll
        for (int ks = 0; ks < 2; ++ks) {
            short8 av[4], bv[4];
#pragma unroll
            for (int r = 0; r < 4; ++r) {
                const int row = wm + r * 16 + lr;
                av[r] = *(const short8*)&sm.At[row * 64 + (((ks * 4 + quad) ^ (row & 7)) * 8)];
            }
#pragma unroll
            for (int c = 0; c < 4; ++c) {
                const int row = wn + c * 16 + lr;
                bv[c] = *(const short8*)&sm.Bt[row * 64 + (((ks * 4 + quad) ^ (row & 7)) * 8)];
            }
#pragma unroll
            for (int r = 0; r < 4; ++r)
#pragma unroll
                for (int c = 0; c < 4; ++c)
                    acc[r][c] = __builtin_amdgcn_mfma_f32_16x16x32_bf16(av[r], bv[c], acc[r][c], 0, 0, 0);
        }
        __syncthreads();
    }
}

// C/D layout col=lane&15, row=quad*4+reg  [verified m89/m91]
#define EPI_COORDS()                               \
    const int tid = threadIdx.x;                   \
    const int wid = tid >> 6;                      \
    const int lane = tid & 63;                     \
    const int quad = lane >> 4;                    \
    const int lr = lane & 15;                      \
    const int wm = (wid & 1) * 64;                 \
    const int wn = (wid >> 1) * 64;

// ---------------------------------------------------------------- phase kernels
__global__ __launch_bounds__(256, 3) void proj_kernel(
    const unsigned short* __restrict__ in_bf,
    const unsigned short* __restrict__ WqT, const unsigned short* __restrict__ WkT,
    const unsigned short* __restrict__ WvT, const unsigned short* __restrict__ WrT,
    const unsigned short* __restrict__ pe,
    const float* __restrict__ cb, const float* __restrict__ rb,
    unsigned short* __restrict__ qc, unsigned short* __restrict__ qr,
    unsigned short* __restrict__ kbf, unsigned short* __restrict__ vT,
    unsigned short* __restrict__ rk)
{
    __shared__ SMem sm;
    EPI_COORDS();
    const long TD = (long)T_ * D_;
    const long DT = (long)D_ * T_;
    f32x4 acc[4][4];
    const int t = blockIdx.x;   // 0..1599
    if (t < 1024) {                           // qc/qr (t<512) and k (t<1024)
        const int r = t & 511;
        const int it = r >> 2, jt = r & 3;
        const unsigned short* Bw = (t < 512) ? WqT : WkT;
        gemm_core(in_bf + (long)it * 128 * 512, 512, Bw + (long)jt * 128 * 512, 512, 512, sm, acc);
        const int i0 = it * 128, j0 = jt * 128;
#pragma unroll
        for (int r2 = 0; r2 < 4; ++r2)
#pragma unroll
            for (int c2 = 0; c2 < 4; ++c2) {
                const int gi = i0 + wm + r2 * 16 + quad * 4;
                const int gj = j0 + wn + c2 * 16 + lr;
#pragma unroll
                for (int tt = 0; tt < 4; ++tt) {
                    const float v = acc[r2][c2][tt];
                    const long row = gi + tt;
                    if (t < 512) {
                        qc[row * 512 + gj] = f2bf(v + cb[gj]);
                        qr[row * 512 + gj] = f2bf(v + rb[gj]);
                    } else {
                        kbf[row * 512 + gj] = f2bf(v);
                    }
                }
            }
    } else if (t < 1536) {                    // vT[b] = Wv^T @ in[b]^T
        const int r = t - 1024;
        const int z = r >> 6, rr = r & 63;
        const int it = rr >> 4, jt = rr & 15;
        const int i0 = it * 128, j0 = jt * 128;
        gemm_core(WvT + (long)i0 * 512, 512, in_bf + (long)z * TD + (long)j0 * 512, 512, 512, sm, acc);
#pragma unroll
        for (int r2 = 0; r2 < 4; ++r2)
#pragma unroll
            for (int c2 = 0; c2 < 4; ++c2) {
                const int gi = i0 + wm + r2 * 16 + quad * 4;
                const int gj = j0 + wn + c2 * 16 + lr;
#pragma unroll
                for (int tt = 0; tt < 4; ++tt)
                    vT[(long)z * DT + (long)(gi + tt) * 2048 + gj] = f2bf(acc[r2][c2][tt]);
            }
    } else {                                  // rk = pe @ Wrel
        const int r = t - 1536;
        const int it = r >> 2, jt = r & 3;
        const int i0 = it * 128, j0 = jt * 128;
        gemm_core(pe + (long)i0 * 512, 512, WrT + (long)j0 * 512, 512, 512, sm, acc);
#pragma unroll
        for (int r2 = 0; r2 < 4; ++r2)
#pragma unroll
            for (int c2 = 0; c2 < 4; ++c2) {
                const int gi = i0 + wm + r2 * 16 + quad * 4;
                const int gj = j0 + wn + c2 * 16 + lr;
#pragma unroll
                for (int tt = 0; tt < 4; ++tt)
                    rk[(long)(gi + tt) * 512 + gj] = f2bf(acc[r2][c2][tt]);
            }
    }
}

// content scores -> C8b (bf16, pre-scaled, causal tiles) and rel scores -> R8b
// (bf16, SHIFTED + PRE-SCALED: Rs[i][j] = bf16(SC*R[i][p]), j = p + i - 2047).
// Both logit streams std~1, |max|~5 -> bf16 rounding ~0.004-0.008, same order
// as the P-bf16 rounding already in the pipeline (R4: absmax unchanged).
// XCD-aware: z = blockIdx & 7 so each XCD works one batch.
__global__ __launch_bounds__(256, 3) void score_kernel(
    const unsigned short* __restrict__ qc, const unsigned short* __restrict__ qr,
    const unsigned short* __restrict__ kbf, const unsigned short* __restrict__ rk,
    unsigned short* __restrict__ C8b, unsigned short* __restrict__ R8b)
{
    __shared__ SMem sm;
    EPI_COORDS();
    const long TD = (long)T_ * D_;
    f32x4 acc[4][4];
    const int z = blockIdx.x & 7;             // XCD cluster by batch
    const int rr = blockIdx.x >> 3;           // 0..271
    if (rr < 136) {
        const int r = rr;
        int a = (int)((sqrtf(8.f * (float)r + 1.f) - 1.f) * 0.5f);
        if ((a + 1) * (a + 2) / 2 <= r) ++a;
        if (a * (a + 1) / 2 > r) --a;
        const int b = r - a * (a + 1) / 2;    // b <= a (causal tiles)
        const int i0 = a * 128, j0 = b * 128;
        gemm_core(qc + (long)z * TD + (long)i0 * 512, 512,
                  kbf + (long)z * TD + (long)j0 * 512, 512, 512, sm, acc);
        unsigned short* Cb = C8b + (long)z * 4194304L;
#pragma unroll
        for (int r2 = 0; r2 < 4; ++r2)
#pragma unroll
            for (int c2 = 0; c2 < 4; ++c2) {
                const int gi = i0 + wm + r2 * 16 + quad * 4;
                const int gj = j0 + wn + c2 * 16 + lr;
#pragma unroll
                for (int tt = 0; tt < 4; ++tt)
                    Cb[(long)(gi + tt) * 2048 + gj] = f2bf(acc[r2][c2][tt] * SC_);
            }
    } else {
        const int r = rr - 136;
        int u = (int)((sqrtf(8.f * (float)r + 1.f) - 1.f) * 0.5f);
        if ((u + 1) * (u + 2) / 2 <= r) ++u;
        if (u * (u + 1) / 2 > r) --u;
        const int v2 = r - u * (u + 1) / 2;   // v2 <= u
        const int a = u, b = 15 - u + v2;     // tiles covering p >= T-1-i
        const int i0 = a * 128, p0 = b * 128;
        gemm_core(qr + (long)z * TD + (long)i0 * 512, 512,
                  rk + (long)p0 * 512, 512, 512, sm, acc);
        unsigned short* Rb = R8b + (long)z * 4194304L;
#pragma unroll
        for (int r2 = 0; r2 < 4; ++r2)
#pragma unroll
            for (int c2 = 0; c2 < 4; ++c2) {
                const int gi = i0 + wm + r2 * 16 + quad * 4;
                const int gp = p0 + wn + c2 * 16 + lr;
#pragma unroll
                for (int tt = 0; tt < 4; ++tt) {
                    const int row = gi + tt;
                    const int j = gp + row - 2047;       // shifted column
                    if (j >= 0)
                        Rb[(long)row * 2048 + j] = f2bf(acc[r2][c2][tt] * SC_);
                }
            }
    }
}

// row softmax: S[i,j] = bf2f(C8b[i,j]) + bf2f(R8b[i,j]) (pre-scaled, aligned).
// P (bf16) written IN PLACE over C8b (row stride 2048) — safe: all loads of
// the row complete before the first store (reduction barriers in between).
// One row per block, grid (2048, 8). us4 loads, us4 stores.
__global__ __launch_bounds__(256) void softmax_kernel(unsigned short* __restrict__ C8b,
                                                      const unsigned short* __restrict__ R8b) {
    const int i = blockIdx.x;
    unsigned short* Cm = C8b + (long)blockIdx.y * 4194304L;
    const unsigned short* Rm = R8b + (long)blockIdx.y * 4194304L;
    __shared__ float s[2048];
    __shared__ float red[5];
    const int tid = threadIdx.x;
    const int wid = tid >> 6;
    const int n = i + 1;
    const int n4 = (n + 3) >> 2;
    const us4* c4 = (const us4*)(Cm + (long)i * 2048);
    const us4* r4 = (const us4*)(Rm + (long)i * 2048);
    float lmax = -3.0e38f;
    for (int j4 = tid; j4 < n4; j4 += 256) {
        const us4 c = c4[j4];
        const us4 r = r4[j4];
        f32x4 v;
#pragma unroll
        for (int e = 0; e < 4; ++e) {
            const int j = j4 * 4 + e;
            const float vv = (j < n) ? bf2f(c[e]) + bf2f(r[e]) : -3.0e38f;  // mask tail/poison
            v[e] = vv;
            lmax = fmaxf(lmax, vv);
        }
        *(f32x4*)&s[j4 * 4] = v;
    }
    for (int o = 32; o; o >>= 1) lmax = fmaxf(lmax, __shfl_down(lmax, o));
    if ((tid & 63) == 0) red[wid] = lmax;
    __syncthreads();
    if (tid == 0) red[4] = fmaxf(fmaxf(red[0], red[1]), fmaxf(red[2], red[3]));
    __syncthreads();
    const float m = red[4];
    float lsum = 0.f;
    for (int j4 = tid; j4 < n4; j4 += 256) {
        f32x4 v = *(f32x4*)&s[j4 * 4];
#pragma unroll
        for (int e = 0; e < 4; ++e) {
            const float x = __expf(v[e] - m);      // masked lanes -> exp(-inf)=0
            v[e] = x;
            lsum += x;
        }
        *(f32x4*)&s[j4 * 4] = v;
    }
    for (int o = 32; o; o >>= 1) lsum += __shfl_down(lsum, o);
    if ((tid & 63) == 0) red[wid] = lsum;
    __syncthreads();
    if (tid == 0) red[4] = 1.0f / (red[0] + red[1] + red[2] + red[3]);
    __syncthreads();
    const float inv = red[4];
    us4* Prow = (us4*)(Cm + (long)i * 2048);      // in-place over C8b
    const int iend4 = (((i >> 7) + 1) << 7) >> 2; // zero-pad to 128-tile edge
    for (int j4 = tid; j4 < iend4; j4 += 256) {
        us4 ov;
#pragma unroll
        for (int e = 0; e < 4; ++e) {
            const int j = j4 * 4 + e;
            const float pv = (j < n) ? s[j] * inv : 0.f;
            ov[e] = f2bf(pv);
        }
        Prow[j4] = ov;
    }
}

// out = P @ V. XCD-aware z clustering. All 512 blocks are co-resident
// (2/CU), so dispatch ORDER doesn't balance — PAIRING does: block c pairs
// with c+256 on the same CU; map it so paired K-sums are constant:
// q<32 -> it=15-(q>>2) (K=2048..1152), q>=32 -> it=(q>>2)-8 (K=128..1024).
// Every CU then gets 17 work-units instead of worst-case 24.
__global__ __launch_bounds__(256, 3) void pv_kernel(
    const unsigned short* __restrict__ C8b, const unsigned short* __restrict__ vT,
    float* __restrict__ out)
{
    __shared__ SMem sm;
    EPI_COORDS();
    const long TD = (long)T_ * D_;
    const long DT = (long)D_ * T_;
    f32x4 acc[4][4];
    const int z = blockIdx.x & 7;             // XCD cluster by batch
    const int q = blockIdx.x >> 3;            // 0..63
    const int s4 = q >> 2;                    // 0..15
    const int it = (q < 32) ? (15 - s4) : (s4 - 8);
    const int jt = q & 3;
    const int i0 = it * 128, j0 = jt * 128;
    const int kmax = i0 + 128;                // causal K-limit (multiple of 128)
    gemm_core(C8b + (long)z * 4194304L + (long)i0 * 2048, 2048,
              vT + (long)z * DT + (long)j0 * 2048, 2048, kmax, sm, acc);
#pragma unroll
    for (int r2 = 0; r2 < 4; ++r2)
#pragma unroll
        for (int c2 = 0; c2 < 4; ++c2) {
            const int gi = i0 + wm + r2 * 16 + quad * 4;
            const int gj = j0 + wn + c2 * 16 + lr;
#pragma unroll
            for (int tt = 0; tt < 4; ++tt)
                out[(long)z * TD + (long)(gi + tt) * 512 + gj] = acc[r2][c2][tt];
        }
}

// ---------------------------------------------------------------- launcher
extern "C" void kernel_launch(void* const* d_in, const int* in_sizes, int n_in,
                              void* d_out, int out_size, void* d_ws, size_t ws_size,
                              hipStream_t stream) {
    (void)in_sizes; (void)n_in; (void)out_size; (void)ws_size;
    const float* inputs = (const float*)d_in[0];
    const float* Wq = (const float*)d_in[1];
    const float* Wk = (const float*)d_in[2];
    const float* Wv = (const float*)d_in[3];
    const float* Wrel = (const float*)d_in[4];
    const float* cb = (const float*)d_in[5];
    const float* rb = (const float*)d_in[6];
    float* out = (float*)d_out;

    // workspace layout (~223 MB)
    char* ws = (char*)d_ws;
    unsigned short* in_bf = (unsigned short*)ws;                   // 16384x512
    unsigned short* WqT = (unsigned short*)(ws + 16777216);
    unsigned short* WkT = WqT + 262144;
    unsigned short* WvT = WkT + 262144;
    unsigned short* WrT = WvT + 262144;
    unsigned short* pe  = WrT + 262144;                            // 2048x512
    unsigned short* qc  = pe + 1048576;                            // 16384x512
    unsigned short* qr  = qc + 8388608;
    unsigned short* kbf = qr + 8388608;
    unsigned short* vT  = kbf + 8388608;                           // 8 x 512x2048
    unsigned short* rk  = vT + 8388608;                            // 2048x512
    unsigned short* C8b = rk + 1048576;                            // 8 x 2048x2048 bf16
    unsigned short* R8b = C8b + 33554432;                          // 8 x 2048x2048 bf16

    prep_all<<<dim3(10240), 256, 0, stream>>>(inputs, Wq, Wk, Wv, Wrel,
                                              in_bf, WqT, WkT, WvT, WrT, pe);
    proj_kernel<<<dim3(1600), 256, 0, stream>>>(in_bf, WqT, WkT, WvT, WrT, pe, cb, rb,
                                                qc, qr, kbf, vT, rk);
    score_kernel<<<dim3(2176), 256, 0, stream>>>(qc, qr, kbf, rk, C8b, R8b);
    softmax_kernel<<<dim3(2048, 8), 256, 0, stream>>>(C8b, R8b);
    pv_kernel<<<dim3(512), 256, 0, stream>>>(C8b, vT, out);
}